// Round 4
// baseline (58.668 us; speedup 1.0000x reference)
//
#include <hip/hip_runtime.h>
#include <math.h>

#define M       32
#define IDIM    64
#define DIN     68
#define HDIM    128

// workspace float offsets
// A4 layout:   ws[OFF_A   + ((i4*DIN + d) << 2) + k] = A[i4*4+k][d]   (i4<16, d<68, k<4)
// Wvo4 layout: ws[OFF_WVO + ((d4*IDIM + j) << 2) + k] = Wvo[d4*4+k][j] (d4<17, j<64, k<4)
#define OFF_A     0        // 4352 floats
#define OFF_U0    4352     // u0[d] (68)
#define OFF_G     4420     // g[i] (64)
#define OFF_C0    4484     // c0 (1)
#define OFF_WVO   4608     // 4352 floats
#define OFF_OUTB  8960     // outb[j] (64)
#define WS_FLOATS 9024     // = 2256 float4
#define WS_F4     2256

__global__ __launch_bounds__(256)
void ga_precompute(const float* __restrict__ Wq, const float* __restrict__ bq,
                   const float* __restrict__ Wk, const float* __restrict__ bk,
                   const float* __restrict__ Wv, const float* __restrict__ bv,
                   const float* __restrict__ Wo, const float* __restrict__ bo,
                   float* __restrict__ ws) {
  int t = blockIdx.x * 256 + threadIdx.x;
  const float4* Wq4 = (const float4*)Wq;   // [64][32]
  const float4* Wk4 = (const float4*)Wk;   // [68][32]
  if (t < 4352) {                       // A in A4 layout
    int k = t & 3, rem = t >> 2;
    int d = rem % DIN, i4 = rem / DIN;
    int i = i4 * 4 + k;
    float acc = 0.f;
    #pragma unroll 8
    for (int h4 = 0; h4 < 32; ++h4) {
      float4 a = Wq4[i*32+h4], b = Wk4[d*32+h4];
      acc = fmaf(a.x, b.x, acc); acc = fmaf(a.y, b.y, acc);
      acc = fmaf(a.z, b.z, acc); acc = fmaf(a.w, b.w, acc);
    }
    ws[OFF_A + t] = acc;
  } else if (t < 4420) {                // u0
    int d = t - 4352;
    float acc = 0.f;
    for (int h = 0; h < HDIM; ++h) acc = fmaf(Wk[d*HDIM+h], bq[h], acc);
    ws[OFF_U0 + d] = acc;
  } else if (t < 4484) {                // g
    int i = t - 4420;
    float acc = 0.f;
    for (int h = 0; h < HDIM; ++h) acc = fmaf(Wq[i*HDIM+h], bk[h], acc);
    ws[OFF_G + i] = acc;
  } else if (t == 4484) {               // c0
    float acc = 0.f;
    for (int h = 0; h < HDIM; ++h) acc = fmaf(bq[h], bk[h], acc);
    ws[OFF_C0] = acc;
  } else if (t >= OFF_WVO && t < OFF_WVO + 4352) {   // Wvo in Wvo4 layout
    int e = t - OFF_WVO;
    int k = e & 3, rem = e >> 2;
    int j = rem & 63, d4 = rem >> 6;
    int d = d4 * 4 + k;
    float acc = 0.f;
    #pragma unroll 8
    for (int h = 0; h < HDIM; ++h) acc = fmaf(Wv[d*HDIM+h], Wo[h*IDIM+j], acc);
    ws[OFF_WVO + e] = acc;
  } else if (t >= OFF_OUTB && t < OFF_OUTB + IDIM) { // outb
    int j = t - OFF_OUTB;
    float acc = bo[j];
    for (int h = 0; h < HDIM; ++h) acc = fmaf(bv[h], Wo[h*IDIM+j], acc);
    ws[OFF_OUTB + j] = acc;
  }
}

// 512 threads = 8 waves, one row per wave. Consts (36KB) staged to LDS once
// per block via registers; raw s_barrier with lgkmcnt(0) only so younger HBM
// zreg loads stay in flight. launch_bounds(512,3): VGPR cap ~85 (live ~75,
// NO spill — (512,6)'s cap of 42 spilled 23MB of scratch in R2).
// Const reads use ds_read_b128 (contiguous 16B/lane): 33 b128 vs 132 b32.
__global__ __launch_bounds__(512, 3)
void ga_main(const float* __restrict__ ego,
             const float* __restrict__ nz,
             const float* __restrict__ rp,
             const int*   __restrict__ mask,
             const float* __restrict__ ws,
             float* __restrict__ out) {
  __shared__ float cst   [WS_FLOATS];   // 36096 B
  __shared__ float u_lds [8 * 72];
  __shared__ float sc_lds[8 * 32];
  __shared__ float fb_lds[8 * 72];

  const int tid  = threadIdx.x;
  const int wave = tid >> 6;
  const int lane = tid & 63;
  const int row  = __builtin_amdgcn_readfirstlane(blockIdx.x * 8 + wave);

  const int ub  = wave * 72;
  const int sb  = wave * 32;
  const int fbb = wave * 72;

  // ---- const staging loads FIRST (oldest in vmcnt order) ----
  const float4* ws4 = (const float4*)ws;
  float4 creg[5];
  #pragma unroll
  for (int k = 0; k < 5; ++k) {
    int idx = tid + k * 512;
    if (idx < WS_F4) creg[k] = ws4[idx];
  }

  // ---- HBM staging loads (younger: stay in flight across barrier) ----
  const float4* zsrc4 = (const float4*)(nz + (size_t)row * (M * IDIM));
  float4 zreg[8];
  #pragma unroll
  for (int it = 0; it < 8; ++it) zreg[it] = zsrc4[it * 64 + lane];
  const float4 rpreg = ((const float4*)(rp + (size_t)row * (M * 4)))[lane & 31];
  const int    mreg  = mask[row * M + (lane & 31)];

  // ---- park consts in LDS; barrier WITHOUT vmcnt drain ----
  {
    float4* lds4 = (float4*)cst;
    #pragma unroll
    for (int k = 0; k < 5; ++k) {
      int idx = tid + k * 512;
      if (idx < WS_F4) lds4[idx] = creg[k];
    }
  }
  asm volatile("s_waitcnt lgkmcnt(0)" ::: "memory");
  __builtin_amdgcn_s_barrier();
  asm volatile("" ::: "memory");

  // ---- phase 1: u[d] = ego @ A + u0, lane = d (A4 from LDS, b128) ----
  const float* egoR = ego + (size_t)row * IDIM;   // wave-uniform -> scalar loads
  {
    float ua0 = 0.f, ua1 = 0.f, ua2 = 0.f, ua3 = 0.f;
    #pragma unroll 8
    for (int i4 = 0; i4 < 16; ++i4) {
      const float4 av = *(const float4*)&cst[OFF_A + ((i4 * DIN + lane) << 2)];
      ua0 = fmaf(egoR[i4 * 4],     av.x, ua0);
      ua1 = fmaf(egoR[i4 * 4 + 1], av.y, ua1);
      ua2 = fmaf(egoR[i4 * 4 + 2], av.z, ua2);
      ua3 = fmaf(egoR[i4 * 4 + 3], av.w, ua3);
    }
    u_lds[ub + lane] = ((ua0 + ua1) + (ua2 + ua3)) + cst[OFF_U0 + lane];
  }
  // tail dims u[64..67]: 16-lane cooperative dots (one b128 each)
  {
    int t4 = lane >> 4, i4 = lane & 15;
    const float4 av = *(const float4*)&cst[OFF_A + ((i4 * DIN + IDIM + t4) << 2)];
    float pt = egoR[i4 * 4] * av.x;
    pt = fmaf(egoR[i4 * 4 + 1], av.y, pt);
    pt = fmaf(egoR[i4 * 4 + 2], av.z, pt);
    pt = fmaf(egoR[i4 * 4 + 3], av.w, pt);
    pt += __shfl_xor(pt, 1);
    pt += __shfl_xor(pt, 2);
    pt += __shfl_xor(pt, 4);
    pt += __shfl_xor(pt, 8);
    if (i4 == 0) u_lds[ub + IDIM + t4] = pt + cst[OFF_U0 + IDIM + t4];
  }
  // cterm = ego.g + c0
  float cterm;
  {
    float pc = egoR[lane] * cst[OFF_G + lane];
    pc += __shfl_xor(pc, 1);
    pc += __shfl_xor(pc, 2);
    pc += __shfl_xor(pc, 4);
    pc += __shfl_xor(pc, 8);
    pc += __shfl_xor(pc, 16);
    pc += __shfl_xor(pc, 32);
    cterm = pc + cst[OFF_C0];
  }

  asm volatile("" ::: "memory");   // in-wave DS order

  // ---- phase 2: scores from registers (zreg arrives here) ----
  const float4 u4 = *(const float4*)&u_lds[ub + (lane & 15) * 4];
  #pragma unroll
  for (int it = 0; it < 8; ++it) {
    float p = zreg[it].x * u4.x;
    p = fmaf(zreg[it].y, u4.y, p);
    p = fmaf(zreg[it].z, u4.z, p);
    p = fmaf(zreg[it].w, u4.w, p);
    p += __shfl_xor(p, 1);
    p += __shfl_xor(p, 2);
    p += __shfl_xor(p, 4);
    p += __shfl_xor(p, 8);
    if ((lane & 15) == 0) sc_lds[sb + it * 4 + (lane >> 4)] = p;
  }

  asm volatile("" ::: "memory");

  const float uh0 = u_lds[ub + 64], uh1 = u_lds[ub + 65];
  const float uh2 = u_lds[ub + 66], uh3 = u_lds[ub + 67];
  float sraw = sc_lds[sb + (lane & 31)] + cterm;
  sraw = fmaf(rpreg.x, uh0, sraw);
  sraw = fmaf(rpreg.y, uh1, sraw);
  sraw = fmaf(rpreg.z, uh2, sraw);
  sraw = fmaf(rpreg.w, uh3, sraw);

  float s = (mreg != 0) ? sraw * 0.088388347648318447f : -1e9f;  // 1/sqrt(128)
  float mx = s;
  mx = fmaxf(mx, __shfl_xor(mx, 1));
  mx = fmaxf(mx, __shfl_xor(mx, 2));
  mx = fmaxf(mx, __shfl_xor(mx, 4));
  mx = fmaxf(mx, __shfl_xor(mx, 8));
  mx = fmaxf(mx, __shfl_xor(mx, 16));
  float e = __expf(s - mx);
  float se = e;
  se += __shfl_xor(se, 1);
  se += __shfl_xor(se, 2);
  se += __shfl_xor(se, 4);
  se += __shfl_xor(se, 8);
  se += __shfl_xor(se, 16);
  const float w = e / se;

  // ---- phase 3: fbar from registers ----
  float p40 = 0.f, p41 = 0.f, p42 = 0.f, p43 = 0.f;
  #pragma unroll
  for (int it = 0; it < 8; ++it) {
    float wit = __shfl(w, it * 4 + (lane >> 4));
    p40 = fmaf(wit, zreg[it].x, p40);
    p41 = fmaf(wit, zreg[it].y, p41);
    p42 = fmaf(wit, zreg[it].z, p42);
    p43 = fmaf(wit, zreg[it].w, p43);
  }
  p40 += __shfl_xor(p40, 16);  p40 += __shfl_xor(p40, 32);
  p41 += __shfl_xor(p41, 16);  p41 += __shfl_xor(p41, 32);
  p42 += __shfl_xor(p42, 16);  p42 += __shfl_xor(p42, 32);
  p43 += __shfl_xor(p43, 16);  p43 += __shfl_xor(p43, 32);
  if (lane < 16) {
    float4 fv; fv.x = p40; fv.y = p41; fv.z = p42; fv.w = p43;
    *(float4*)&fb_lds[fbb + lane * 4] = fv;
  }
  // rp contribution to fbar[64..67]
  {
    float pr0 = w * rpreg.x, pr1 = w * rpreg.y, pr2 = w * rpreg.z, pr3 = w * rpreg.w;
    pr0 += __shfl_xor(pr0, 1); pr1 += __shfl_xor(pr1, 1);
    pr2 += __shfl_xor(pr2, 1); pr3 += __shfl_xor(pr3, 1);
    pr0 += __shfl_xor(pr0, 2); pr1 += __shfl_xor(pr1, 2);
    pr2 += __shfl_xor(pr2, 2); pr3 += __shfl_xor(pr3, 2);
    pr0 += __shfl_xor(pr0, 4); pr1 += __shfl_xor(pr1, 4);
    pr2 += __shfl_xor(pr2, 4); pr3 += __shfl_xor(pr3, 4);
    pr0 += __shfl_xor(pr0, 8); pr1 += __shfl_xor(pr1, 8);
    pr2 += __shfl_xor(pr2, 8); pr3 += __shfl_xor(pr3, 8);
    pr0 += __shfl_xor(pr0, 16); pr1 += __shfl_xor(pr1, 16);
    pr2 += __shfl_xor(pr2, 16); pr3 += __shfl_xor(pr3, 16);
    if (lane == 0) {
      float4 fv; fv.x = pr0; fv.y = pr1; fv.z = pr2; fv.w = pr3;
      *(float4*)&fb_lds[fbb + IDIM] = fv;
    }
  }

  asm volatile("" ::: "memory");

  // ---- phase 4: out[j] = fbar @ Wvo + outb, lane = j (Wvo4 from LDS, b128) ----
  float oa0 = 0.f, oa1 = 0.f, oa2 = 0.f, oa3 = 0.f;
  #pragma unroll 8
  for (int d4 = 0; d4 < 17; ++d4) {
    const float4 wv = *(const float4*)&cst[OFF_WVO + ((d4 * IDIM + lane) << 2)];
    const float4 fv = *(const float4*)&fb_lds[fbb + d4 * 4];   // uniform broadcast
    oa0 = fmaf(fv.x, wv.x, oa0);
    oa1 = fmaf(fv.y, wv.y, oa1);
    oa2 = fmaf(fv.z, wv.z, oa2);
    oa3 = fmaf(fv.w, wv.w, oa3);
  }
  out[(size_t)row * IDIM + lane] = ((oa0 + oa1) + (oa2 + oa3)) + cst[OFF_OUTB + lane];
}

extern "C" void kernel_launch(void* const* d_in, const int* in_sizes, int n_in,
                              void* d_out, int out_size, void* d_ws, size_t ws_size,
                              hipStream_t stream) {
  const float* ego = (const float*)d_in[0];
  const float* nz  = (const float*)d_in[1];
  const float* rp  = (const float*)d_in[2];
  const int*   mk  = (const int*)d_in[3];
  const float* Wq  = (const float*)d_in[4];
  const float* bq  = (const float*)d_in[5];
  const float* Wk  = (const float*)d_in[6];
  const float* bk  = (const float*)d_in[7];
  const float* Wv  = (const float*)d_in[8];
  const float* bv  = (const float*)d_in[9];
  const float* Wo  = (const float*)d_in[10];
  const float* bo  = (const float*)d_in[11];
  float* ws = (float*)d_ws;   // needs WS_FLOATS*4 = 36096 bytes
  float* o  = (float*)d_out;

  const int nrows = in_sizes[0] / IDIM;   // 16384

  ga_precompute<<<(WS_FLOATS + 255) / 256, 256, 0, stream>>>(
      Wq, bq, Wk, bk, Wv, bv, Wo, bo, ws);
  ga_main<<<nrows / 8, 512, 0, stream>>>(ego, nz, rp, mk, ws, o);
}

// Round 5
// 53.271 us; speedup vs baseline: 1.1013x; 1.1013x over previous
//
#include <hip/hip_runtime.h>
#include <math.h>

#define M       32
#define IDIM    64
#define DIN     68
#define HDIM    128

// ws float offsets. A4 and Wvo4 are CONTIGUOUS (staged to LDS as 34x1KB chunks).
// A4:   ws[((i4*DIN + d) << 2) + k]           = A[4*i4+k][d]    (i4<16, d<68, k<4)
// Wvo4: ws[WS_WVO4 + ((d4*IDIM + j) << 2) + k] = Wvo[4*d4+k][j] (d4<17, j<64, k<4)
#define WS_A4     0        // 4352 floats
#define WS_WVO4   4352     // 4352 floats
#define WS_U0     8704     // 68
#define WS_G      8772     // 64
#define WS_C0     8836     // 1
#define WS_OUTB   8840     // 64
#define WS_FLOATS 8904

#define CST_FLOATS 8704    // A4+Wvo4 in LDS: 34816 B = 34 chunks of 1KB
#define CST_WVO    4352

__global__ __launch_bounds__(256)
void ga_precompute(const float* __restrict__ Wq, const float* __restrict__ bq,
                   const float* __restrict__ Wk, const float* __restrict__ bk,
                   const float* __restrict__ Wv, const float* __restrict__ bv,
                   const float* __restrict__ Wo, const float* __restrict__ bo,
                   float* __restrict__ ws) {
  int t = blockIdx.x * 256 + threadIdx.x;
  const float4* Wq4 = (const float4*)Wq;   // [64][32]
  const float4* Wk4 = (const float4*)Wk;   // [68][32]
  if (t < 4352) {                       // A in A4 layout
    int k = t & 3, rem = t >> 2;
    int d = rem % DIN, i4 = rem / DIN;
    int i = i4 * 4 + k;
    float acc = 0.f;
    #pragma unroll 8
    for (int h4 = 0; h4 < 32; ++h4) {
      float4 a = Wq4[i*32+h4], b = Wk4[d*32+h4];
      acc = fmaf(a.x, b.x, acc); acc = fmaf(a.y, b.y, acc);
      acc = fmaf(a.z, b.z, acc); acc = fmaf(a.w, b.w, acc);
    }
    ws[WS_A4 + t] = acc;
  } else if (t < 8704) {                // Wvo in Wvo4 layout
    int e = t - WS_WVO4;
    int k = e & 3, rem = e >> 2;
    int j = rem & 63, d4 = rem >> 6;
    int d = d4 * 4 + k;
    float acc = 0.f;
    #pragma unroll 8
    for (int h = 0; h < HDIM; ++h) acc = fmaf(Wv[d*HDIM+h], Wo[h*IDIM+j], acc);
    ws[WS_WVO4 + e] = acc;
  } else if (t < 8772) {                // u0
    int d = t - WS_U0;
    float acc = 0.f;
    for (int h = 0; h < HDIM; ++h) acc = fmaf(Wk[d*HDIM+h], bq[h], acc);
    ws[WS_U0 + d] = acc;
  } else if (t < 8836) {                // g
    int i = t - WS_G;
    float acc = 0.f;
    for (int h = 0; h < HDIM; ++h) acc = fmaf(Wq[i*HDIM+h], bk[h], acc);
    ws[WS_G + i] = acc;
  } else if (t == 8836) {               // c0
    float acc = 0.f;
    for (int h = 0; h < HDIM; ++h) acc = fmaf(bq[h], bk[h], acc);
    ws[WS_C0] = acc;
  } else if (t < WS_FLOATS) {           // outb
    int j = t - WS_OUTB;
    float acc = bo[j];
    for (int h = 0; h < HDIM; ++h) acc = fmaf(bv[h], Wo[h*IDIM+j], acc);
    ws[WS_OUTB + j] = acc;
  }
}

// 512 threads = 8 waves, one row per wave. A4+Wvo4 (34KB) staged to LDS via
// global_load_lds (zero VGPR cost, vmcnt-counted). glls are oldest VMEM;
// s_waitcnt vmcnt(10) retires exactly them; raw s_barrier keeps the 10
// per-row loads (z0..z7, rp, mask) in flight. NO runtime-indexed register
// arrays anywhere (R2-R4's scratch spill: SROA vs unroll ordering).
__global__ __launch_bounds__(512, 4)
void ga_main(const float* __restrict__ ego,
             const float* __restrict__ nz,
             const float* __restrict__ rp,
             const int*   __restrict__ mask,
             const float* __restrict__ ws,
             float* __restrict__ out) {
  __shared__ float cst   [CST_FLOATS];  // 34816 B
  __shared__ float u_lds [8 * 72];
  __shared__ float sc_lds[8 * 32];
  __shared__ float fb_lds[8 * 72];

  const int tid  = threadIdx.x;
  const int wave = tid >> 6;
  const int lane = tid & 63;
  const int row  = __builtin_amdgcn_readfirstlane(blockIdx.x * 8 + wave);

  const int ub  = wave * 72;
  const int sb  = wave * 32;
  const int fbb = wave * 72;

  // ---- const staging: global_load_lds, 34 chunks of 1KB, oldest in vmcnt ----
  #define GLL(K) do { int c = wave + 8*(K); if (c < 34)                         \
    __builtin_amdgcn_global_load_lds(                                           \
      (const __attribute__((address_space(1))) void*)(ws + c*256 + lane*4),     \
      (__attribute__((address_space(3))) void*)(cst + c*256), 16, 0, 0); } while(0)
  GLL(0); GLL(1); GLL(2); GLL(3); GLL(4);
  #undef GLL
  __builtin_amdgcn_sched_barrier(0);

  // ---- per-row loads (younger: stay in flight across barrier): 10 VMEM ----
  const float4* zsrc4 = (const float4*)(nz + (size_t)row * (M * IDIM));
  float4 z0 = zsrc4[0*64 + lane], z1 = zsrc4[1*64 + lane];
  float4 z2 = zsrc4[2*64 + lane], z3 = zsrc4[3*64 + lane];
  float4 z4 = zsrc4[4*64 + lane], z5 = zsrc4[5*64 + lane];
  float4 z6 = zsrc4[6*64 + lane], z7 = zsrc4[7*64 + lane];
  const float4 rpreg = ((const float4*)(rp + (size_t)row * (M * 4)))[lane & 31];
  const int    mreg  = mask[row * M + (lane & 31)];

  __builtin_amdgcn_sched_barrier(0);
  asm volatile("s_waitcnt vmcnt(10)" ::: "memory");   // glls done; row loads in flight
  __builtin_amdgcn_s_barrier();
  asm volatile("" ::: "memory");

  // ---- phase 1: u[d] = ego @ A + u0, lane = d (A4 from LDS, b128) ----
  const float* egoR = ego + (size_t)row * IDIM;   // wave-uniform -> scalar loads
  {
    float ua0 = 0.f, ua1 = 0.f, ua2 = 0.f, ua3 = 0.f;
    #pragma unroll 8
    for (int i4 = 0; i4 < 16; ++i4) {
      const float4 av = *(const float4*)&cst[(i4 * DIN + lane) << 2];
      ua0 = fmaf(egoR[i4 * 4],     av.x, ua0);
      ua1 = fmaf(egoR[i4 * 4 + 1], av.y, ua1);
      ua2 = fmaf(egoR[i4 * 4 + 2], av.z, ua2);
      ua3 = fmaf(egoR[i4 * 4 + 3], av.w, ua3);
    }
    u_lds[ub + lane] = ((ua0 + ua1) + (ua2 + ua3)) + ws[WS_U0 + lane];
  }
  // tail dims u[64..67]: 16-lane cooperative dots (one b128 each)
  {
    int t4 = lane >> 4, i4 = lane & 15;
    const float4 av = *(const float4*)&cst[(i4 * DIN + IDIM + t4) << 2];
    float pt = egoR[i4 * 4] * av.x;
    pt = fmaf(egoR[i4 * 4 + 1], av.y, pt);
    pt = fmaf(egoR[i4 * 4 + 2], av.z, pt);
    pt = fmaf(egoR[i4 * 4 + 3], av.w, pt);
    pt += __shfl_xor(pt, 1);
    pt += __shfl_xor(pt, 2);
    pt += __shfl_xor(pt, 4);
    pt += __shfl_xor(pt, 8);
    if (i4 == 0) u_lds[ub + IDIM + t4] = pt + ws[WS_U0 + IDIM + t4];
  }
  // cterm = ego.g + c0
  float cterm;
  {
    float pc = egoR[lane] * ws[WS_G + lane];
    pc += __shfl_xor(pc, 1);
    pc += __shfl_xor(pc, 2);
    pc += __shfl_xor(pc, 4);
    pc += __shfl_xor(pc, 8);
    pc += __shfl_xor(pc, 16);
    pc += __shfl_xor(pc, 32);
    cterm = pc + ws[WS_C0];
  }

  asm volatile("" ::: "memory");   // in-wave DS order

  // ---- phase 2: scores from registers (z* arrive here) ----
  const float4 u4 = *(const float4*)&u_lds[ub + (lane & 15) * 4];
  #define SC(IT, Z) do {                                                  \
    float p = (Z).x * u4.x;                                               \
    p = fmaf((Z).y, u4.y, p);                                             \
    p = fmaf((Z).z, u4.z, p);                                             \
    p = fmaf((Z).w, u4.w, p);                                             \
    p += __shfl_xor(p, 1); p += __shfl_xor(p, 2);                         \
    p += __shfl_xor(p, 4); p += __shfl_xor(p, 8);                         \
    if ((lane & 15) == 0) sc_lds[sb + (IT) * 4 + (lane >> 4)] = p;        \
  } while (0)
  SC(0, z0); SC(1, z1); SC(2, z2); SC(3, z3);
  SC(4, z4); SC(5, z5); SC(6, z6); SC(7, z7);
  #undef SC

  asm volatile("" ::: "memory");

  const float uh0 = u_lds[ub + 64], uh1 = u_lds[ub + 65];
  const float uh2 = u_lds[ub + 66], uh3 = u_lds[ub + 67];
  float sraw = sc_lds[sb + (lane & 31)] + cterm;
  sraw = fmaf(rpreg.x, uh0, sraw);
  sraw = fmaf(rpreg.y, uh1, sraw);
  sraw = fmaf(rpreg.z, uh2, sraw);
  sraw = fmaf(rpreg.w, uh3, sraw);

  float s = (mreg != 0) ? sraw * 0.088388347648318447f : -1e9f;  // 1/sqrt(128)
  float mx = s;
  mx = fmaxf(mx, __shfl_xor(mx, 1));
  mx = fmaxf(mx, __shfl_xor(mx, 2));
  mx = fmaxf(mx, __shfl_xor(mx, 4));
  mx = fmaxf(mx, __shfl_xor(mx, 8));
  mx = fmaxf(mx, __shfl_xor(mx, 16));
  float e = __expf(s - mx);
  float se = e;
  se += __shfl_xor(se, 1);
  se += __shfl_xor(se, 2);
  se += __shfl_xor(se, 4);
  se += __shfl_xor(se, 8);
  se += __shfl_xor(se, 16);
  const float w = e / se;

  // ---- phase 3: fbar from registers ----
  float p40 = 0.f, p41 = 0.f, p42 = 0.f, p43 = 0.f;
  #define FB(IT, Z) do {                                                  \
    float wit = __shfl(w, (IT) * 4 + (lane >> 4));                        \
    p40 = fmaf(wit, (Z).x, p40);                                          \
    p41 = fmaf(wit, (Z).y, p41);                                          \
    p42 = fmaf(wit, (Z).z, p42);                                          \
    p43 = fmaf(wit, (Z).w, p43);                                          \
  } while (0)
  FB(0, z0); FB(1, z1); FB(2, z2); FB(3, z3);
  FB(4, z4); FB(5, z5); FB(6, z6); FB(7, z7);
  #undef FB
  p40 += __shfl_xor(p40, 16);  p40 += __shfl_xor(p40, 32);
  p41 += __shfl_xor(p41, 16);  p41 += __shfl_xor(p41, 32);
  p42 += __shfl_xor(p42, 16);  p42 += __shfl_xor(p42, 32);
  p43 += __shfl_xor(p43, 16);  p43 += __shfl_xor(p43, 32);
  if (lane < 16) {
    float4 fv; fv.x = p40; fv.y = p41; fv.z = p42; fv.w = p43;
    *(float4*)&fb_lds[fbb + lane * 4] = fv;
  }
  // rp contribution to fbar[64..67]
  {
    float pr0 = w * rpreg.x, pr1 = w * rpreg.y, pr2 = w * rpreg.z, pr3 = w * rpreg.w;
    pr0 += __shfl_xor(pr0, 1); pr1 += __shfl_xor(pr1, 1);
    pr2 += __shfl_xor(pr2, 1); pr3 += __shfl_xor(pr3, 1);
    pr0 += __shfl_xor(pr0, 2); pr1 += __shfl_xor(pr1, 2);
    pr2 += __shfl_xor(pr2, 2); pr3 += __shfl_xor(pr3, 2);
    pr0 += __shfl_xor(pr0, 4); pr1 += __shfl_xor(pr1, 4);
    pr2 += __shfl_xor(pr2, 4); pr3 += __shfl_xor(pr3, 4);
    pr0 += __shfl_xor(pr0, 8); pr1 += __shfl_xor(pr1, 8);
    pr2 += __shfl_xor(pr2, 8); pr3 += __shfl_xor(pr3, 8);
    pr0 += __shfl_xor(pr0, 16); pr1 += __shfl_xor(pr1, 16);
    pr2 += __shfl_xor(pr2, 16); pr3 += __shfl_xor(pr3, 16);
    if (lane == 0) {
      float4 fv; fv.x = pr0; fv.y = pr1; fv.z = pr2; fv.w = pr3;
      *(float4*)&fb_lds[fbb + IDIM] = fv;
    }
  }

  asm volatile("" ::: "memory");

  // ---- phase 4: out[j] = fbar @ Wvo + outb, lane = j (Wvo4 from LDS, b128) ----
  float oa0 = 0.f, oa1 = 0.f, oa2 = 0.f, oa3 = 0.f;
  #pragma unroll 8
  for (int d4 = 0; d4 < 17; ++d4) {
    const float4 wv = *(const float4*)&cst[CST_WVO + ((d4 * IDIM + lane) << 2)];
    const float4 fv = *(const float4*)&fb_lds[fbb + d4 * 4];   // uniform broadcast
    oa0 = fmaf(fv.x, wv.x, oa0);
    oa1 = fmaf(fv.y, wv.y, oa1);
    oa2 = fmaf(fv.z, wv.z, oa2);
    oa3 = fmaf(fv.w, wv.w, oa3);
  }
  out[(size_t)row * IDIM + lane] = ((oa0 + oa1) + (oa2 + oa3)) + ws[WS_OUTB + lane];
}

extern "C" void kernel_launch(void* const* d_in, const int* in_sizes, int n_in,
                              void* d_out, int out_size, void* d_ws, size_t ws_size,
                              hipStream_t stream) {
  const float* ego = (const float*)d_in[0];
  const float* nz  = (const float*)d_in[1];
  const float* rp  = (const float*)d_in[2];
  const int*   mk  = (const int*)d_in[3];
  const float* Wq  = (const float*)d_in[4];
  const float* bq  = (const float*)d_in[5];
  const float* Wk  = (const float*)d_in[6];
  const float* bk  = (const float*)d_in[7];
  const float* Wv  = (const float*)d_in[8];
  const float* bv  = (const float*)d_in[9];
  const float* Wo  = (const float*)d_in[10];
  const float* bo  = (const float*)d_in[11];
  float* ws = (float*)d_ws;   // needs WS_FLOATS*4 = 35616 bytes
  float* o  = (float*)d_out;

  const int nrows = in_sizes[0] / IDIM;   // 16384

  ga_precompute<<<(WS_FLOATS + 255) / 256, 256, 0, stream>>>(
      Wq, bq, Wk, bk, Wv, bv, Wo, bo, ws);
  ga_main<<<nrows / 8, 512, 0, stream>>>(ego, nz, rp, mk, ws, o);
}

// Round 7
// 41.290 us; speedup vs baseline: 1.4209x; 1.2902x over previous
//
#include <hip/hip_runtime.h>
#include <math.h>

#define M       32
#define IDIM    64
#define DIN     68
#define HDIM    128

// ws float offsets. A4 and Wvo4 are CONTIGUOUS (staged to LDS as 34x1KB chunks).
// A4:   ws[((i4*DIN + d) << 2) + k]            = A[4*i4+k][d]    (i4<16, d<68, k<4)
// Wvo4: ws[WS_WVO4 + ((d4*IDIM + j) << 2) + k] = Wvo[4*d4+k][j]  (d4<17, j<64, k<4)
#define WS_A4     0        // 4352 floats
#define WS_WVO4   4352     // 4352 floats
#define WS_U0     8704     // 68
#define WS_G      8772     // 64
#define WS_C0     8836     // 1
#define WS_OUTB   8840     // 64
#define WS_FLOATS 8904

#define CST_FLOATS 8704    // A4+Wvo4 in LDS: 34816 B = 34 chunks of 1KB
#define CST_WVO    4352

__global__ __launch_bounds__(256)
void ga_precompute(const float* __restrict__ Wq, const float* __restrict__ bq,
                   const float* __restrict__ Wk, const float* __restrict__ bk,
                   const float* __restrict__ Wv, const float* __restrict__ bv,
                   const float* __restrict__ Wo, const float* __restrict__ bo,
                   float* __restrict__ ws) {
  int t = blockIdx.x * 256 + threadIdx.x;
  const float4* Wq4 = (const float4*)Wq;   // [64][32]
  const float4* Wk4 = (const float4*)Wk;   // [68][32]
  if (t < 4352) {                       // A in A4 layout
    int k = t & 3, rem = t >> 2;
    int d = rem % DIN, i4 = rem / DIN;
    int i = i4 * 4 + k;
    float acc = 0.f;
    #pragma unroll 8
    for (int h4 = 0; h4 < 32; ++h4) {
      float4 a = Wq4[i*32+h4], b = Wk4[d*32+h4];
      acc = fmaf(a.x, b.x, acc); acc = fmaf(a.y, b.y, acc);
      acc = fmaf(a.z, b.z, acc); acc = fmaf(a.w, b.w, acc);
    }
    ws[WS_A4 + t] = acc;
  } else if (t < 8704) {                // Wvo in Wvo4 layout
    int e = t - WS_WVO4;
    int k = e & 3, rem = e >> 2;
    int j = rem & 63, d4 = rem >> 6;
    int d = d4 * 4 + k;
    float acc = 0.f;
    #pragma unroll 8
    for (int h = 0; h < HDIM; ++h) acc = fmaf(Wv[d*HDIM+h], Wo[h*IDIM+j], acc);
    ws[WS_WVO4 + e] = acc;
  } else if (t < 8772) {                // u0
    int d = t - WS_U0;
    float acc = 0.f;
    for (int h = 0; h < HDIM; ++h) acc = fmaf(Wk[d*HDIM+h], bq[h], acc);
    ws[WS_U0 + d] = acc;
  } else if (t < 8836) {                // g
    int i = t - WS_G;
    float acc = 0.f;
    for (int h = 0; h < HDIM; ++h) acc = fmaf(Wq[i*HDIM+h], bk[h], acc);
    ws[WS_G + i] = acc;
  } else if (t == 8836) {               // c0
    float acc = 0.f;
    for (int h = 0; h < HDIM; ++h) acc = fmaf(bq[h], bk[h], acc);
    ws[WS_C0] = acc;
  } else if (t < WS_FLOATS) {           // outb
    int j = t - WS_OUTB;
    float acc = bo[j];
    for (int h = 0; h < HDIM; ++h) acc = fmaf(bv[h], Wo[h*IDIM+j], acc);
    ws[WS_OUTB + j] = acc;
  }
}

// DPP sum over each 16-lane group (VALU pipe, no DS): xor1, xor2, ror4, ror8.
// All 16 lanes end with the group sum. CTRL must be an immediate -> template.
template <int CTRL>
__device__ __forceinline__ float dpp_add(float x) {
  int t = __builtin_amdgcn_update_dpp(0, __float_as_int(x), CTRL, 0xF, 0xF, true);
  return x + __int_as_float(t);
}
__device__ __forceinline__ float red16(float x) {
  x = dpp_add<0xB1>(x);    // quad_perm [1,0,3,2]  (xor 1)
  x = dpp_add<0x4E>(x);    // quad_perm [2,3,0,1]  (xor 2)
  x = dpp_add<0x124>(x);   // row_ror:4
  x = dpp_add<0x128>(x);   // row_ror:8
  return x;
}

// 512 threads = 8 waves, one row per wave. A4+Wvo4 (34KB) -> LDS via
// global_load_lds (counted vmcnt; row loads stay in flight across barrier).
// Lane space: t4 = lane>>4 (m-subgroup), l = lane&15 (d-chunk).
// z_it = feats[m=4*it+t4][4l..4l+3]. Scores/softmax/weights live per-lane in
// (it,t4) space: zero LDS round-trips for sc/softmax/w-broadcast; all 4-level
// reductions are DPP (VALU), only xor16/32 crossings use shfl (DS).
__global__ __launch_bounds__(512, 2)
void ga_main(const float* __restrict__ ego,
             const float* __restrict__ nz,
             const float* __restrict__ rp,
             const int*   __restrict__ mask,
             const float* __restrict__ ws,
             float* __restrict__ out) {
  __shared__ float cst   [CST_FLOATS];  // 34816 B
  __shared__ float u_lds [8 * 64];      // 2048 B
  __shared__ float w_lds [8 * 32];      // 1024 B
  __shared__ float fb_lds[8 * 64];      // 2048 B

  const int tid  = threadIdx.x;
  const int wave = tid >> 6;
  const int lane = tid & 63;
  const int t4   = lane >> 4;
  const int l    = lane & 15;
  const int row  = __builtin_amdgcn_readfirstlane(blockIdx.x * 8 + wave);

  // ---- const staging: global_load_lds, 34 chunks of 1KB (oldest in vmcnt) ----
  #define GLL(K) do { int c = wave + 8*(K); if (c < 34)                         \
    __builtin_amdgcn_global_load_lds(                                           \
      (const __attribute__((address_space(1))) void*)(ws + c*256 + lane*4),     \
      (__attribute__((address_space(3))) void*)(cst + c*256), 16, 0, 0); } while(0)
  GLL(0); GLL(1); GLL(2); GLL(3); GLL(4);
  #undef GLL
  __builtin_amdgcn_sched_barrier(0);

  // ---- per-row loads (younger: stay in flight across barrier): 11 VMEM ----
  const float4* zsrc4 = (const float4*)(nz + (size_t)row * (M * IDIM));
  float4 z0 = zsrc4[0*64 + lane], z1 = zsrc4[1*64 + lane];
  float4 z2 = zsrc4[2*64 + lane], z3 = zsrc4[3*64 + lane];
  float4 z4 = zsrc4[4*64 + lane], z5 = zsrc4[5*64 + lane];
  float4 z6 = zsrc4[6*64 + lane], z7 = zsrc4[7*64 + lane];
  const float4* rpsrc = (const float4*)(rp + (size_t)row * (M * 4));
  const float4 rpa = rpsrc[4 * (lane & 7) + t4];   // rp row for m=4*(l&7)+t4
  const float4 rpb = rpsrc[lane & 31];             // rp row for m=lane&31
  const int    mreg = mask[row * M + (lane & 31)];

  __builtin_amdgcn_sched_barrier(0);
  asm volatile("s_waitcnt vmcnt(11)" ::: "memory");   // glls done; row loads fly
  __builtin_amdgcn_s_barrier();
  asm volatile("" ::: "memory");

  // ---- phase 1: u[d] = ego @ A + u0, lane = d (A4 from LDS, b128) ----
  const float* egoR = ego + (size_t)row * IDIM;   // wave-uniform -> s_loads
  {
    float ua0 = 0.f, ua1 = 0.f, ua2 = 0.f, ua3 = 0.f;
    #pragma unroll 8
    for (int i4 = 0; i4 < 16; ++i4) {
      const float4 av = *(const float4*)&cst[(i4 * DIN + lane) << 2];
      ua0 = fmaf(egoR[i4 * 4],     av.x, ua0);
      ua1 = fmaf(egoR[i4 * 4 + 1], av.y, ua1);
      ua2 = fmaf(egoR[i4 * 4 + 2], av.z, ua2);
      ua3 = fmaf(egoR[i4 * 4 + 3], av.w, ua3);
    }
    u_lds[wave * 64 + lane] = ((ua0 + ua1) + (ua2 + ua3)) + ws[WS_U0 + lane];
  }
  // tail u[64..67]: DPP 16-group reduce, then readlane -> uniform
  float uh0, uh1, uh2, uh3;
  {
    const float4 av = *(const float4*)&cst[(l * DIN + IDIM + t4) << 2];
    float pt = egoR[l * 4] * av.x;
    pt = fmaf(egoR[l * 4 + 1], av.y, pt);
    pt = fmaf(egoR[l * 4 + 2], av.z, pt);
    pt = fmaf(egoR[l * 4 + 3], av.w, pt);
    pt = red16(pt);
    int pti = __float_as_int(pt);
    uh0 = __int_as_float(__builtin_amdgcn_readlane(pti, 0))  + ws[WS_U0 + 64];
    uh1 = __int_as_float(__builtin_amdgcn_readlane(pti, 16)) + ws[WS_U0 + 65];
    uh2 = __int_as_float(__builtin_amdgcn_readlane(pti, 32)) + ws[WS_U0 + 66];
    uh3 = __int_as_float(__builtin_amdgcn_readlane(pti, 48)) + ws[WS_U0 + 67];
  }
  // cterm = ego.g + c0
  float cterm;
  {
    float pc = egoR[lane] * ws[WS_G + lane];
    pc = red16(pc);
    pc += __shfl_xor(pc, 16);
    pc += __shfl_xor(pc, 32);
    cterm = pc + ws[WS_C0];
  }

  asm volatile("" ::: "memory");   // u_lds write -> read (in-wave DS order)

  // ---- phase 2: scores in (it,t4) space ----
  const float4 u4 = *(const float4*)&u_lds[wave * 64 + l * 4];
  const float rpdot = fmaf(rpa.w, uh3, fmaf(rpa.z, uh2,
                      fmaf(rpa.y, uh1, rpa.x * uh0)));
  const unsigned int mbits  = (unsigned int)__ballot(mreg != 0);
  const unsigned int mshift = mbits >> t4;   // bit 4*it = mask of m=4*it+t4

  #define SC(IT, Z) float s##IT; {                                        \
    float p = (Z).x * u4.x;                                               \
    p = fmaf((Z).y, u4.y, p);                                             \
    p = fmaf((Z).z, u4.z, p);                                             \
    p = fmaf((Z).w, u4.w, p);                                             \
    p += (l == (IT)) ? rpdot : 0.f;                                       \
    p = red16(p);                                                         \
    s##IT = ((mshift >> (4*(IT))) & 1u)                                   \
          ? (p + cterm) * 0.088388347648318447f : -1e9f; }
  SC(0, z0) SC(1, z1) SC(2, z2) SC(3, z3)
  SC(4, z4) SC(5, z5) SC(6, z6) SC(7, z7)
  #undef SC

  // softmax over 32 m's: 8 in-lane + cross-group (xor16, xor32)
  float mx = fmaxf(fmaxf(fmaxf(s0, s1), fmaxf(s2, s3)),
                   fmaxf(fmaxf(s4, s5), fmaxf(s6, s7)));
  mx = fmaxf(mx, __shfl_xor(mx, 16));
  mx = fmaxf(mx, __shfl_xor(mx, 32));
  float e0 = __expf(s0 - mx), e1 = __expf(s1 - mx);
  float e2 = __expf(s2 - mx), e3 = __expf(s3 - mx);
  float e4 = __expf(s4 - mx), e5 = __expf(s5 - mx);
  float e6 = __expf(s6 - mx), e7 = __expf(s7 - mx);
  float se = ((e0 + e1) + (e2 + e3)) + ((e4 + e5) + (e6 + e7));
  se += __shfl_xor(se, 16);
  se += __shfl_xor(se, 32);
  const float rse = __builtin_amdgcn_rcpf(se);
  const float w0 = e0 * rse, w1 = e1 * rse, w2 = e2 * rse, w3 = e3 * rse;
  const float w4 = e4 * rse, w5 = e5 * rse, w6 = e6 * rse, w7 = e7 * rse;

  // ---- phase 3: fbar[4l+k] — weights already in-lane, no broadcast ----
  float p40 = 0.f, p41 = 0.f, p42 = 0.f, p43 = 0.f;
  #define FB(W, Z) do {                                                   \
    p40 = fmaf((W), (Z).x, p40);                                          \
    p41 = fmaf((W), (Z).y, p41);                                          \
    p42 = fmaf((W), (Z).z, p42);                                          \
    p43 = fmaf((W), (Z).w, p43);                                          \
  } while (0);
  FB(w0, z0) FB(w1, z1) FB(w2, z2) FB(w3, z3)
  FB(w4, z4) FB(w5, z5) FB(w6, z6) FB(w7, z7)
  #undef FB
  p40 += __shfl_xor(p40, 16);  p40 += __shfl_xor(p40, 32);
  p41 += __shfl_xor(p41, 16);  p41 += __shfl_xor(p41, 32);
  p42 += __shfl_xor(p42, 16);  p42 += __shfl_xor(p42, 32);
  p43 += __shfl_xor(p43, 16);  p43 += __shfl_xor(p43, 32);

  // park w (layout [t4][it] so the write is 2 contiguous b128) and fbar
  if (l == 0) {
    float4 wa; wa.x = w0; wa.y = w1; wa.z = w2; wa.w = w3;
    float4 wb; wb.x = w4; wb.y = w5; wb.z = w6; wb.w = w7;
    *(float4*)&w_lds[wave * 32 + t4 * 8]     = wa;
    *(float4*)&w_lds[wave * 32 + t4 * 8 + 4] = wb;
  }
  if (lane < 16) {
    float4 fv; fv.x = p40; fv.y = p41; fv.z = p42; fv.w = p43;
    *(float4*)&fb_lds[wave * 64 + l * 4] = fv;
  }
  asm volatile("" ::: "memory");

  // rp tail: fbar[64+k] = sum_m w_m*rp[m][k] (uniform in-reg afterwards)
  const int mm = lane & 31;
  const float wm = w_lds[wave * 32 + (mm & 3) * 8 + (mm >> 2)];
  float pr0 = wm * rpb.x, pr1 = wm * rpb.y, pr2 = wm * rpb.z, pr3 = wm * rpb.w;
  pr0 = red16(pr0); pr0 += __shfl_xor(pr0, 16);
  pr1 = red16(pr1); pr1 += __shfl_xor(pr1, 16);
  pr2 = red16(pr2); pr2 += __shfl_xor(pr2, 16);
  pr3 = red16(pr3); pr3 += __shfl_xor(pr3, 16);

  // ---- phase 4: out[j] = fbar @ Wvo + outb, lane = j (Wvo4 from LDS) ----
  float oa0 = 0.f, oa1 = 0.f, oa2 = 0.f, oa3 = 0.f;
  #pragma unroll 8
  for (int d4 = 0; d4 < 16; ++d4) {
    const float4 wv = *(const float4*)&cst[CST_WVO + ((d4 * IDIM + lane) << 2)];
    const float4 fv = *(const float4*)&fb_lds[wave * 64 + d4 * 4]; // broadcast
    oa0 = fmaf(fv.x, wv.x, oa0);
    oa1 = fmaf(fv.y, wv.y, oa1);
    oa2 = fmaf(fv.z, wv.z, oa2);
    oa3 = fmaf(fv.w, wv.w, oa3);
  }
  {
    const float4 wv = *(const float4*)&cst[CST_WVO + ((16 * IDIM + lane) << 2)];
    oa0 = fmaf(pr0, wv.x, oa0);
    oa1 = fmaf(pr1, wv.y, oa1);
    oa2 = fmaf(pr2, wv.z, oa2);
    oa3 = fmaf(pr3, wv.w, oa3);
  }
  out[(size_t)row * IDIM + lane] = ((oa0 + oa1) + (oa2 + oa3)) + ws[WS_OUTB + lane];
}

extern "C" void kernel_launch(void* const* d_in, const int* in_sizes, int n_in,
                              void* d_out, int out_size, void* d_ws, size_t ws_size,
                              hipStream_t stream) {
  const float* ego = (const float*)d_in[0];
  const float* nz  = (const float*)d_in[1];
  const float* rp  = (const float*)d_in[2];
  const int*   mk  = (const int*)d_in[3];
  const float* Wq  = (const float*)d_in[4];
  const float* bq  = (const float*)d_in[5];
  const float* Wk  = (const float*)d_in[6];
  const float* bk  = (const float*)d_in[7];
  const float* Wv  = (const float*)d_in[8];
  const float* bv  = (const float*)d_in[9];
  const float* Wo  = (const float*)d_in[10];
  const float* bo  = (const float*)d_in[11];
  float* ws = (float*)d_ws;   // needs WS_FLOATS*4 = 35616 bytes
  float* o  = (float*)d_out;

  const int nrows = in_sizes[0] / IDIM;   // 16384

  ga_precompute<<<(WS_FLOATS + 255) / 256, 256, 0, stream>>>(
      Wq, bq, Wk, bk, Wv, bv, Wo, bo, ws);
  ga_main<<<nrows / 8, 512, 0, stream>>>(ego, nz, rp, mk, ws, o);
}

// Round 8
// 37.783 us; speedup vs baseline: 1.5528x; 1.0928x over previous
//
#include <hip/hip_runtime.h>
#include <math.h>

#define M       32
#define IDIM    64
#define DIN     68
#define HDIM    128

// ws float offsets. A4 and Wvo4 are CONTIGUOUS (staged to LDS as 34x1KB chunks).
// A4:   ws[((i4*DIN + d) << 2) + k]            = A[4*i4+k][d]    (i4<16, d<68, k<4)
// Wvo4: ws[WS_WVO4 + ((d4*IDIM + j) << 2) + k] = Wvo[4*d4+k][j]  (d4<17, j<64, k<4)
#define WS_A4     0        // 4352 floats
#define WS_WVO4   4352     // 4352 floats
#define WS_U0     8704     // 68
#define WS_G      8772     // 64
#define WS_C0     8836     // 1
#define WS_OUTB   8840     // 64
#define WS_FLOATS 8904

#define CST_FLOATS 8704    // A4+Wvo4 in LDS: 34816 B = 34 chunks of 1KB
#define CST_WVO    4352

// DPP helpers (VALU pipe, no DS). CTRL must be an immediate -> template.
template <int CTRL>
__device__ __forceinline__ float dpp_add(float x) {
  int t = __builtin_amdgcn_update_dpp(0, __float_as_int(x), CTRL, 0xF, 0xF, true);
  return x + __int_as_float(t);
}
__device__ __forceinline__ float red4(float x) {   // sum over aligned quad
  x = dpp_add<0xB1>(x);    // quad_perm xor1
  x = dpp_add<0x4E>(x);    // quad_perm xor2
  return x;
}
__device__ __forceinline__ float red16(float x) {  // sum over 16-lane group
  x = dpp_add<0xB1>(x);
  x = dpp_add<0x4E>(x);
  x = dpp_add<0x124>(x);   // row_ror:4
  x = dpp_add<0x128>(x);   // row_ror:8
  return x;
}

// 4 threads per output element, each dotting 32 of 128 h's, DPP quad-reduce.
#define SEG_A   0
#define SEG_W   17408
#define SEG_U0  34816
#define SEG_G   35088
#define SEG_OB  35344
#define SEG_C0  35600
#define PRE_T   35601

__global__ __launch_bounds__(256)
void ga_precompute(const float* __restrict__ Wq, const float* __restrict__ bq,
                   const float* __restrict__ Wk, const float* __restrict__ bk,
                   const float* __restrict__ Wv, const float* __restrict__ bv,
                   const float* __restrict__ Wo, const float* __restrict__ bo,
                   float* __restrict__ ws) {
  int t = blockIdx.x * 256 + threadIdx.x;
  if (t >= PRE_T) return;
  const float4* Wq4 = (const float4*)Wq;   // [64][32]
  const float4* Wk4 = (const float4*)Wk;   // [68][32]
  const float4* Wv4 = (const float4*)Wv;   // [68][32]
  const float4* bq4 = (const float4*)bq;   // [32]
  const float4* bk4 = (const float4*)bk;   // [32]
  const int sub = t & 3;
  const int h4b = sub * 8;                 // float4-chunk base of this thread's h-range

  if (t < SEG_W) {                         // A4
    int e = t >> 2;
    int k = e & 3, rem = e >> 2;
    int d = rem % DIN, i4 = rem / DIN;
    int i = i4 * 4 + k;
    float acc = 0.f;
    #pragma unroll
    for (int hh = 0; hh < 8; ++hh) {
      float4 a = Wq4[i*32 + h4b + hh], b = Wk4[d*32 + h4b + hh];
      acc = fmaf(a.x, b.x, acc); acc = fmaf(a.y, b.y, acc);
      acc = fmaf(a.z, b.z, acc); acc = fmaf(a.w, b.w, acc);
    }
    acc = red4(acc);
    if (sub == 0) ws[WS_A4 + e] = acc;
  } else if (t < SEG_U0) {                 // Wvo4
    int e = (t - SEG_W) >> 2;
    int k = e & 3, rem = e >> 2;
    int j = rem & 63, d4 = rem >> 6;
    int d = d4 * 4 + k;
    float acc = 0.f;
    #pragma unroll
    for (int hh = 0; hh < 8; ++hh) {
      float4 v = Wv4[d*32 + h4b + hh];
      int h = (h4b + hh) * 4;
      acc = fmaf(v.x, Wo[(h    )*IDIM + j], acc);
      acc = fmaf(v.y, Wo[(h + 1)*IDIM + j], acc);
      acc = fmaf(v.z, Wo[(h + 2)*IDIM + j], acc);
      acc = fmaf(v.w, Wo[(h + 3)*IDIM + j], acc);
    }
    acc = red4(acc);
    if (sub == 0) ws[WS_WVO4 + e] = acc;
  } else if (t < SEG_G) {                  // u0
    int d = (t - SEG_U0) >> 2;
    float acc = 0.f;
    #pragma unroll
    for (int hh = 0; hh < 8; ++hh) {
      float4 a = Wk4[d*32 + h4b + hh], b = bq4[h4b + hh];
      acc = fmaf(a.x, b.x, acc); acc = fmaf(a.y, b.y, acc);
      acc = fmaf(a.z, b.z, acc); acc = fmaf(a.w, b.w, acc);
    }
    acc = red4(acc);
    if (sub == 0) ws[WS_U0 + d] = acc;
  } else if (t < SEG_OB) {                 // g
    int i = (t - SEG_G) >> 2;
    float acc = 0.f;
    #pragma unroll
    for (int hh = 0; hh < 8; ++hh) {
      float4 a = Wq4[i*32 + h4b + hh], b = bk4[h4b + hh];
      acc = fmaf(a.x, b.x, acc); acc = fmaf(a.y, b.y, acc);
      acc = fmaf(a.z, b.z, acc); acc = fmaf(a.w, b.w, acc);
    }
    acc = red4(acc);
    if (sub == 0) ws[WS_G + i] = acc;
  } else if (t < SEG_C0) {                 // outb
    int j = (t - SEG_OB) >> 2;
    float acc = 0.f;
    #pragma unroll
    for (int hh = 0; hh < 8; ++hh) {
      int h = (h4b + hh) * 4;
      acc = fmaf(bv[h    ], Wo[(h    )*IDIM + j], acc);
      acc = fmaf(bv[h + 1], Wo[(h + 1)*IDIM + j], acc);
      acc = fmaf(bv[h + 2], Wo[(h + 2)*IDIM + j], acc);
      acc = fmaf(bv[h + 3], Wo[(h + 3)*IDIM + j], acc);
    }
    acc = red4(acc);
    if (sub == 0) ws[WS_OUTB + j] = acc + bo[j];
  } else {                                 // c0
    float acc = 0.f;
    for (int h = 0; h < HDIM; ++h) acc = fmaf(bq[h], bk[h], acc);
    ws[WS_C0] = acc;
  }
}

// 512 threads = 8 waves, one row per wave. A4+Wvo4 (34KB) -> LDS via
// global_load_lds (counted vmcnt; row loads stay in flight across barrier).
// Lane space: t4 = lane>>4 (m-subgroup), l = lane&15 (d-chunk).
// z_it = feats[m=4*it+t4][4l..4l+3]. Scores/softmax/weights per-lane in
// (it,t4) space; all 4-level reductions are DPP (VALU).
// launch_bounds(512,4): VGPR cap 64 -> 4 blocks/CU (32 waves, LDS 38.9KB).
__global__ __launch_bounds__(512, 4)
void ga_main(const float* __restrict__ ego,
             const float* __restrict__ nz,
             const float* __restrict__ rp,
             const int*   __restrict__ mask,
             const float* __restrict__ ws,
             float* __restrict__ out) {
  __shared__ float cst   [CST_FLOATS];  // 34816 B
  __shared__ float u_lds [8 * 64];      // 2048 B
  __shared__ float fb_lds[8 * 64];      // 2048 B

  const int tid  = threadIdx.x;
  const int wave = tid >> 6;
  const int lane = tid & 63;
  const int t4   = lane >> 4;
  const int l    = lane & 15;
  const int row  = __builtin_amdgcn_readfirstlane(blockIdx.x * 8 + wave);

  // ---- const staging: global_load_lds, 34 chunks of 1KB (oldest in vmcnt) ----
  #define GLL(K) do { int c = wave + 8*(K); if (c < 34)                         \
    __builtin_amdgcn_global_load_lds(                                           \
      (const __attribute__((address_space(1))) void*)(ws + c*256 + lane*4),     \
      (__attribute__((address_space(3))) void*)(cst + c*256), 16, 0, 0); } while(0)
  GLL(0); GLL(1); GLL(2); GLL(3); GLL(4);
  #undef GLL
  __builtin_amdgcn_sched_barrier(0);

  // ---- per-row loads (younger: stay in flight across barrier): 10 VMEM ----
  const float4* zsrc4 = (const float4*)(nz + (size_t)row * (M * IDIM));
  float4 z0 = zsrc4[0*64 + lane], z1 = zsrc4[1*64 + lane];
  float4 z2 = zsrc4[2*64 + lane], z3 = zsrc4[3*64 + lane];
  float4 z4 = zsrc4[4*64 + lane], z5 = zsrc4[5*64 + lane];
  float4 z6 = zsrc4[6*64 + lane], z7 = zsrc4[7*64 + lane];
  const float4* rpsrc = (const float4*)(rp + (size_t)row * (M * 4));
  const float4 rpa = rpsrc[4 * (lane & 7) + t4];   // rp row for m=4*(l&7)+t4
  const int    mreg = mask[row * M + (lane & 31)];

  __builtin_amdgcn_sched_barrier(0);
  asm volatile("s_waitcnt vmcnt(10)" ::: "memory");   // glls done; row loads fly
  __builtin_amdgcn_s_barrier();
  asm volatile("" ::: "memory");

  // ---- phase 1: u[d] = ego @ A + u0, lane = d (A4 from LDS, b128) ----
  const float* egoR = ego + (size_t)row * IDIM;   // wave-uniform -> s_loads
  {
    float ua0 = 0.f, ua1 = 0.f, ua2 = 0.f, ua3 = 0.f;
    #pragma unroll 8
    for (int i4 = 0; i4 < 16; ++i4) {
      const float4 av = *(const float4*)&cst[(i4 * DIN + lane) << 2];
      ua0 = fmaf(egoR[i4 * 4],     av.x, ua0);
      ua1 = fmaf(egoR[i4 * 4 + 1], av.y, ua1);
      ua2 = fmaf(egoR[i4 * 4 + 2], av.z, ua2);
      ua3 = fmaf(egoR[i4 * 4 + 3], av.w, ua3);
    }
    u_lds[wave * 64 + lane] = ((ua0 + ua1) + (ua2 + ua3)) + ws[WS_U0 + lane];
  }
  // tail u[64..67]: DPP reduce + readlane; fold into rpdot HERE (uh/rpa die)
  float rpdot;
  {
    const float4 av = *(const float4*)&cst[(l * DIN + IDIM + t4) << 2];
    float pt = egoR[l * 4] * av.x;
    pt = fmaf(egoR[l * 4 + 1], av.y, pt);
    pt = fmaf(egoR[l * 4 + 2], av.z, pt);
    pt = fmaf(egoR[l * 4 + 3], av.w, pt);
    pt = red16(pt);
    int pti = __float_as_int(pt);
    float uh0 = __int_as_float(__builtin_amdgcn_readlane(pti, 0))  + ws[WS_U0 + 64];
    float uh1 = __int_as_float(__builtin_amdgcn_readlane(pti, 16)) + ws[WS_U0 + 65];
    float uh2 = __int_as_float(__builtin_amdgcn_readlane(pti, 32)) + ws[WS_U0 + 66];
    float uh3 = __int_as_float(__builtin_amdgcn_readlane(pti, 48)) + ws[WS_U0 + 67];
    rpdot = fmaf(rpa.w, uh3, fmaf(rpa.z, uh2, fmaf(rpa.y, uh1, rpa.x * uh0)));
  }
  // cterm = ego.g + c0
  float cterm;
  {
    float pc = egoR[lane] * ws[WS_G + lane];
    pc = red16(pc);
    pc += __shfl_xor(pc, 16);
    pc += __shfl_xor(pc, 32);
    cterm = pc + ws[WS_C0];
  }

  asm volatile("" ::: "memory");   // u_lds write -> read (in-wave DS order)

  // ---- phase 2: scores in (it,t4) space ----
  const float4 u4 = *(const float4*)&u_lds[wave * 64 + l * 4];
  const unsigned int mbits  = (unsigned int)__ballot(mreg != 0);
  const unsigned int mshift = mbits >> t4;   // bit 4*it = mask of m=4*it+t4

  #define SC(IT, Z) float s##IT; {                                        \
    float p = (Z).x * u4.x;                                               \
    p = fmaf((Z).y, u4.y, p);                                             \
    p = fmaf((Z).z, u4.z, p);                                             \
    p = fmaf((Z).w, u4.w, p);                                             \
    p += (l == (IT)) ? rpdot : 0.f;                                       \
    p = red16(p);                                                         \
    s##IT = ((mshift >> (4*(IT))) & 1u)                                   \
          ? (p + cterm) * 0.088388347648318447f : -1e9f; }
  SC(0, z0) SC(1, z1) SC(2, z2) SC(3, z3)
  SC(4, z4) SC(5, z5) SC(6, z6) SC(7, z7)
  #undef SC

  // softmax over 32 m's: 8 in-lane + cross-group (xor16, xor32)
  float mx = fmaxf(fmaxf(fmaxf(s0, s1), fmaxf(s2, s3)),
                   fmaxf(fmaxf(s4, s5), fmaxf(s6, s7)));
  mx = fmaxf(mx, __shfl_xor(mx, 16));
  mx = fmaxf(mx, __shfl_xor(mx, 32));
  float e0 = __expf(s0 - mx), e1 = __expf(s1 - mx);
  float e2 = __expf(s2 - mx), e3 = __expf(s3 - mx);
  float e4 = __expf(s4 - mx), e5 = __expf(s5 - mx);
  float e6 = __expf(s6 - mx), e7 = __expf(s7 - mx);
  float se = ((e0 + e1) + (e2 + e3)) + ((e4 + e5) + (e6 + e7));
  se += __shfl_xor(se, 16);
  se += __shfl_xor(se, 32);
  const float rse = __builtin_amdgcn_rcpf(se);
  const float w0 = e0 * rse, w1 = e1 * rse, w2 = e2 * rse, w3 = e3 * rse;
  const float w4 = e4 * rse, w5 = e5 * rse, w6 = e6 * rse, w7 = e7 * rse;

  // ---- phase 3: fbar[4l+k] — weights already in-lane, no broadcast ----
  float p40 = 0.f, p41 = 0.f, p42 = 0.f, p43 = 0.f;
  #define FB(W, Z) do {                                                   \
    p40 = fmaf((W), (Z).x, p40);                                          \
    p41 = fmaf((W), (Z).y, p41);                                          \
    p42 = fmaf((W), (Z).z, p42);                                          \
    p43 = fmaf((W), (Z).w, p43);                                          \
  } while (0);
  FB(w0, z0) FB(w1, z1) FB(w2, z2) FB(w3, z3)
  FB(w4, z4) FB(w5, z5) FB(w6, z6) FB(w7, z7)
  #undef FB
  p40 += __shfl_xor(p40, 16);  p40 += __shfl_xor(p40, 32);
  p41 += __shfl_xor(p41, 16);  p41 += __shfl_xor(p41, 32);
  p42 += __shfl_xor(p42, 16);  p42 += __shfl_xor(p42, 32);
  p43 += __shfl_xor(p43, 16);  p43 += __shfl_xor(p43, 32);
  if (lane < 16) {
    float4 fv; fv.x = p40; fv.y = p41; fv.z = p42; fv.w = p43;
    *(float4*)&fb_lds[wave * 64 + l * 4] = fv;
  }

  // rp tail: fbar[64+k] = sum_m w_m*rp[m][k]. This lane's rpa row m=4*(l&7)+t4
  // pairs with its own w_{l&7} (scores are l-uniform within each 16-group).
  // Each m counted twice across the wave -> fold 0.5 into the selected weight.
  float wsel;
  {
    float a0 = (l & 1) ? w1 : w0, a1 = (l & 1) ? w3 : w2;
    float a2 = (l & 1) ? w5 : w4, a3 = (l & 1) ? w7 : w6;
    float b0 = (l & 2) ? a1 : a0, b1 = (l & 2) ? a3 : a2;
    wsel = 0.5f * ((l & 4) ? b1 : b0);
  }
  float pr0 = wsel * rpa.x, pr1 = wsel * rpa.y;
  float pr2 = wsel * rpa.z, pr3 = wsel * rpa.w;
  pr0 = red16(pr0); pr0 += __shfl_xor(pr0, 16); pr0 += __shfl_xor(pr0, 32);
  pr1 = red16(pr1); pr1 += __shfl_xor(pr1, 16); pr1 += __shfl_xor(pr1, 32);
  pr2 = red16(pr2); pr2 += __shfl_xor(pr2, 16); pr2 += __shfl_xor(pr2, 32);
  pr3 = red16(pr3); pr3 += __shfl_xor(pr3, 16); pr3 += __shfl_xor(pr3, 32);

  asm volatile("" ::: "memory");   // fb_lds write -> read

  // ---- phase 4: out[j] = fbar @ Wvo + outb, lane = j (Wvo4 from LDS) ----
  float oa0 = 0.f, oa1 = 0.f, oa2 = 0.f, oa3 = 0.f;
  #pragma unroll 8
  for (int d4 = 0; d4 < 16; ++d4) {
    const float4 wv = *(const float4*)&cst[CST_WVO + ((d4 * IDIM + lane) << 2)];
    const float4 fv = *(const float4*)&fb_lds[wave * 64 + d4 * 4]; // broadcast
    oa0 = fmaf(fv.x, wv.x, oa0);
    oa1 = fmaf(fv.y, wv.y, oa1);
    oa2 = fmaf(fv.z, wv.z, oa2);
    oa3 = fmaf(fv.w, wv.w, oa3);
  }
  {
    const float4 wv = *(const float4*)&cst[CST_WVO + ((16 * IDIM + lane) << 2)];
    oa0 = fmaf(pr0, wv.x, oa0);
    oa1 = fmaf(pr1, wv.y, oa1);
    oa2 = fmaf(pr2, wv.z, oa2);
    oa3 = fmaf(pr3, wv.w, oa3);
  }
  out[(size_t)row * IDIM + lane] = ((oa0 + oa1) + (oa2 + oa3)) + ws[WS_OUTB + lane];
}

extern "C" void kernel_launch(void* const* d_in, const int* in_sizes, int n_in,
                              void* d_out, int out_size, void* d_ws, size_t ws_size,
                              hipStream_t stream) {
  const float* ego = (const float*)d_in[0];
  const float* nz  = (const float*)d_in[1];
  const float* rp  = (const float*)d_in[2];
  const int*   mk  = (const int*)d_in[3];
  const float* Wq  = (const float*)d_in[4];
  const float* bq  = (const float*)d_in[5];
  const float* Wk  = (const float*)d_in[6];
  const float* bk  = (const float*)d_in[7];
  const float* Wv  = (const float*)d_in[8];
  const float* bv  = (const float*)d_in[9];
  const float* Wo  = (const float*)d_in[10];
  const float* bo  = (const float*)d_in[11];
  float* ws = (float*)d_ws;   // needs WS_FLOATS*4 = 35616 bytes
  float* o  = (float*)d_out;

  const int nrows = in_sizes[0] / IDIM;   // 16384

  ga_precompute<<<(PRE_T + 255) / 256, 256, 0, stream>>>(
      Wq, bq, Wk, bk, Wv, bv, Wo, bo, ws);
  ga_main<<<nrows / 8, 512, 0, stream>>>(ego, nz, rp, mk, ws, o);
}